// Round 9
// baseline (104.250 us; speedup 1.0000x reference)
//
#include <hip/hip_runtime.h>

// Batched 3x3 expm(T) @ x, T = sum_m c[b,m]*psi[m]. Scalar Cayley-Hamilton
// pipeline, one batch/thread (R4/R7: multi-batch -> VGPR cliff, regressed;
// R5: LDS-coalesced I/O regressed; R7: __constant__ psi neutral).
//  (1) order-8 Taylor via Horner in the quotient ring (3 FMA/order),
//  (2) two squarings in coefficient space (15 ops each),
//  (3) tail y = b0 x + (b1/4) Tx + (b2/16) T(Tx).
// R9: T-build packed as <2 x float> chains -> v_pk_fma_f32 (30 issues vs
// 54); c loaded as dwordx4+dwordx2 (24B region is always 8-aligned,
// gfx950 unaligned-access handles 8-aligned x4); nontemporal out stores.
typedef float v2f __attribute__((ext_vector_type(2)));
typedef float v4u __attribute__((ext_vector_type(4), aligned(8)));
typedef float v2u __attribute__((ext_vector_type(2), aligned(4)));

__global__ __launch_bounds__(256) void expm_kernel(
    const float* __restrict__ x,
    const float* __restrict__ c,
    const float* __restrict__ psi,
    float* __restrict__ out)
{
    const int b = blockIdx.x * blockDim.x + threadIdx.x;  // B = 2^21 exact

    // ---- c[b,0:6]: 24 B, 8-aligned for every b -> x4 + x2 load ----
    const float* cb = c + (size_t)b * 6;
    const v4u cv4 = *reinterpret_cast<const v4u*>(cb);
    const v2u cv2 = *reinterpret_cast<const v2u*>(cb + 4);
    const float cm[6] = {cv4.x, cv4.y, cv4.z, cv4.w, cv2.x, cv2.y};

    // ---- x[b,0:3]: 12 B, 4-aligned -> x2 + scalar ----
    const float* xb = x + (size_t)b * 3;
    const v2u xv2 = *reinterpret_cast<const v2u*>(xb);
    const float x0 = xv2.x, x1 = xv2.y, x2 = xb[2];

    // ---- T = sum_m c[m]*psi[m]; packed column-pair chains ----
    // pairs (T0,T1)(T2,T3)(T4,T5)(T6,T7) -> v_pk_fma_f32; T8 scalar.
    v2f T01, T23, T45, T67;
    float T8;
    {
        const v2f cm0 = {cm[0], cm[0]};
        T01 = cm0 * v2f{psi[0], psi[1]};
        T23 = cm0 * v2f{psi[2], psi[3]};
        T45 = cm0 * v2f{psi[4], psi[5]};
        T67 = cm0 * v2f{psi[6], psi[7]};
        T8  = cm[0] * psi[8];
#pragma unroll
        for (int m = 1; m < 6; ++m) {
            const v2f cmm = {cm[m], cm[m]};
            const float* pm = psi + m * 9;
            T01 = __builtin_elementwise_fma(cmm, v2f{pm[0], pm[1]}, T01);
            T23 = __builtin_elementwise_fma(cmm, v2f{pm[2], pm[3]}, T23);
            T45 = __builtin_elementwise_fma(cmm, v2f{pm[4], pm[5]}, T45);
            T67 = __builtin_elementwise_fma(cmm, v2f{pm[6], pm[7]}, T67);
            T8  = fmaf(cm[m], pm[8], T8);
        }
    }
    const float T[9] = {T01.x, T01.y, T23.x, T23.y, T45.x, T45.y,
                        T67.x, T67.y, T8};

    // ---- invariants of T, scaled to A = T/4:
    //      char poly: lam^3 = c2v lam^2 + c1v lam + c0v ----
    const float trT = T[0] + T[4] + T[8];
    const float m01 = fmaf(T[0], T[4], -T[1] * T[3]);
    const float m02 = fmaf(T[0], T[8], -T[2] * T[6]);
    const float m12 = fmaf(T[4], T[8], -T[5] * T[7]);
    const float msT = m01 + m02 + m12;
    const float M10 = fmaf(T[3], T[8], -T[5] * T[6]);
    const float M20 = fmaf(T[3], T[7], -T[4] * T[6]);
    const float detT = fmaf(T[0], m12, fmaf(-T[1], M10, T[2] * M20));
    const float c2v = trT * 0.25f;
    const float c1v = msT * -0.0625f;
    const float c0v = detT * 0.015625f;

    // lam^4 fold-back (shared by both squarings)
    const float d2 = fmaf(c2v, c2v, c1v);
    const float d1 = fmaf(c2v, c1v, c0v);
    const float d0 = c2v * c0v;

    // ---- order-8 Taylor, Horner in the quotient ring ----
    const float tk[8] = {1.0f, 1.0f, 0.5f,
                         1.6666667e-1f, 4.1666667e-2f, 8.3333333e-3f,
                         1.3888889e-3f, 1.9841270e-4f};
    float b0 = 2.4801587e-5f, b1 = 0.0f, b2 = 0.0f;  // h = 1/8!
#pragma unroll
    for (int k = 7; k >= 0; --k) {
        const float n0 = fmaf(b2, c0v, tk[k]);  // tk const after unroll
        const float n1 = fmaf(b2, c1v, b0);
        const float n2 = fmaf(b2, c2v, b1);
        b0 = n0; b1 = n1; b2 = n2;
    }

    // ---- two squarings in coefficient space: b <- b^2 mod m ----
#pragma unroll
    for (int s2 = 0; s2 < 2; ++s2) {
        const float q0 = b0 * b0;
        const float q1 = 2.0f * (b0 * b1);
        const float q2 = fmaf(b1, b1, 2.0f * (b0 * b2));
        const float q3 = 2.0f * (b1 * b2);
        const float q4 = b2 * b2;
        b0 = fmaf(d0, q4, fmaf(c0v, q3, q0));
        b1 = fmaf(d1, q4, fmaf(c1v, q3, q1));
        b2 = fmaf(d2, q4, fmaf(c2v, q3, q2));
    }
    // exp(T) = b0 I + b1 A + b2 A^2,  A = T/4
    const float b1q = b1 * 0.25f;
    const float b2q = b2 * 0.0625f;

    // ---- y = b0 x + b1q (Tx) + b2q T(Tx) ----
    const float w0 = fmaf(T[0], x0, fmaf(T[1], x1, T[2] * x2));
    const float w1 = fmaf(T[3], x0, fmaf(T[4], x1, T[5] * x2));
    const float w2 = fmaf(T[6], x0, fmaf(T[7], x1, T[8] * x2));
    const float v0 = fmaf(T[0], w0, fmaf(T[1], w1, T[2] * w2));
    const float v1 = fmaf(T[3], w0, fmaf(T[4], w1, T[5] * w2));
    const float v2 = fmaf(T[6], w0, fmaf(T[7], w1, T[8] * w2));

    // ---- nontemporal stores (out is write-once) ----
    float* ob = out + (size_t)b * 3;
    __builtin_nontemporal_store(fmaf(b0, x0, fmaf(b1q, w0, b2q * v0)), ob + 0);
    __builtin_nontemporal_store(fmaf(b0, x1, fmaf(b1q, w1, b2q * v1)), ob + 1);
    __builtin_nontemporal_store(fmaf(b0, x2, fmaf(b1q, w2, b2q * v2)), ob + 2);
}

extern "C" void kernel_launch(void* const* d_in, const int* in_sizes, int n_in,
                              void* d_out, int out_size, void* d_ws, size_t ws_size,
                              hipStream_t stream) {
    const float* x   = (const float*)d_in[0];  // [B,3,1]
    const float* c   = (const float*)d_in[1];  // [B,6]
    const float* psi = (const float*)d_in[2];  // [6,3,3]
    float* out = (float*)d_out;                // [B,3,1]

    const int B = in_sizes[1] / 6;  // 2097152 = 2^21, divisible by 256
    const int block = 256;
    const int grid = B / block;
    expm_kernel<<<grid, block, 0, stream>>>(x, c, psi, out);
}